// Round 4
// baseline (765.397 us; speedup 1.0000x reference)
//
#include <hip/hip_runtime.h>
#include <hip/hip_bf16.h>
#include <stdint.h>
#include <stddef.h>

// GCNConv: out = S (X W^T + 1 b^T), S = D^-1/2 (A+I) D^-1/2
// Linearity: out = (S X) W^T + (S 1) b^T  -> aggregate FIRST, then GEMM.
// Input dtypes are detected ON DEVICE (fp32 vs bf16 for x/W/b; int64 vs int32
// for edge_index) and all kernels branch wave-uniformly on the flags.
// Y = S X lives in d_out (in the output dtype); strip_gemm overwrites d_out
// in place, race-free by 32-row block ownership. ws use ~4 MB.

#define D_DIM 1024

typedef __bf16 bf16x8 __attribute__((ext_vector_type(8)));
typedef __bf16 bf16x4 __attribute__((ext_vector_type(4)));
typedef float  f32x4  __attribute__((ext_vector_type(4)));

// ---------------- dtype detection ----------------
// flags[0]: x is fp32. flags[1]: W/b are fp32. flags[2]: edges are int64.
// fp32 data read as bf16 pairs: low halves are uniform mantissa bits ->
// exponent-all-ones (NaN/Inf pattern) at ~1/256 rate. Real bf16 normals: never.
// int64 edges (< 2^31): every odd 32-bit word is 0.

__global__ void detect_kernel(const unsigned int* __restrict__ xw,
                              const unsigned int* __restrict__ ww,
                              const unsigned int* __restrict__ ew,
                              int* __restrict__ flags) {
  __shared__ int s[3];
  int t = threadIdx.x;
  if (t < 3) s[t] = 0;
  __syncthreads();
  int nx = 0, nw = 0, ze = 0;
  for (int i = t; i < 8192; i += 256) {
    if ((xw[i] & 0x7f80u) == 0x7f80u) nx++;
    if ((ww[i] & 0x7f80u) == 0x7f80u) nw++;
    if (ew[2 * i + 1] == 0u) ze++;
  }
  atomicAdd(&s[0], nx);
  atomicAdd(&s[1], nw);
  atomicAdd(&s[2], ze);
  __syncthreads();
  if (t == 0) {
    flags[0] = (s[0] >= 3) ? 1 : 0;
    flags[1] = (s[1] >= 3) ? 1 : 0;
    flags[2] = (s[2] >= 8000) ? 1 : 0;  // 8192 sampled odd words
  }
}

// ---------------- CSR construction ----------------

__global__ void zero_cnt_kernel(int* cnt, int n) {
  int i = blockIdx.x * blockDim.x + threadIdx.x;
  if (i < n) cnt[i] = 0;
}

__global__ void count_deg_kernel(const void* __restrict__ ei, int E,
                                 const int* __restrict__ flags,
                                 int* __restrict__ cnt) {
  int e = blockIdx.x * blockDim.x + threadIdx.x;
  if (e < E) {
    int r = flags[2] ? (int)((const long long*)ei)[e] : ((const int*)ei)[e];
    atomicAdd(&cnt[r], 1);
  }
}

// Single-block Hillis-Steele scan over node counts -> row_ptr, cursor, dinv.
__global__ void scan_kernel(const int* __restrict__ cnt, int n,
                            int* __restrict__ row_ptr, int* __restrict__ cursor,
                            float* __restrict__ dinv) {
  __shared__ int sdata[1024];
  __shared__ int carry_s;
  int t = threadIdx.x;
  if (t == 0) carry_s = 0;
  __syncthreads();
  for (int base = 0; base < n; base += 1024) {
    int idx = base + t;
    int v = (idx < n) ? cnt[idx] : 0;
    sdata[t] = v;
    __syncthreads();
    for (int off = 1; off < 1024; off <<= 1) {
      int add = (t >= off) ? sdata[t - off] : 0;
      __syncthreads();
      sdata[t] += add;
      __syncthreads();
    }
    int incl = sdata[t];
    int carry = carry_s;
    if (idx < n) {
      int excl = carry + incl - v;
      row_ptr[idx] = excl;
      cursor[idx]  = excl;
      dinv[idx] = rsqrtf((float)(v + 1));  // +1 self-loop (deg from rows)
    }
    __syncthreads();
    if (t == 1023) carry_s = carry + incl;
    __syncthreads();
  }
  if (t == 0) row_ptr[n] = carry_s;
}

__global__ void scatter_kernel(const void* __restrict__ ei, int E,
                               const int* __restrict__ flags,
                               int* __restrict__ cursor,
                               int* __restrict__ cols_out) {
  int e = blockIdx.x * blockDim.x + threadIdx.x;
  if (e < E) {
    int r, c;
    if (flags[2]) {
      const long long* p = (const long long*)ei;
      r = (int)p[e]; c = (int)p[e + E];
    } else {
      const int* p = (const int*)ei;
      r = p[e]; c = p[e + E];
    }
    int pos = atomicAdd(&cursor[r], 1);
    cols_out[pos] = c;
  }
}

// ---------------- canonicalize W (bf16) and bias (fp32) ----------------

__global__ void conv_w_kernel(const void* __restrict__ W,
                              const void* __restrict__ b,
                              const int* __restrict__ flags,
                              unsigned short* __restrict__ Wb,
                              float* __restrict__ biasf) {
  int i = blockIdx.x * blockDim.x + threadIdx.x;  // < 1M
  int wfp = flags[1];
  if (wfp) {
    __bf16 h = (__bf16)((const float*)W)[i];
    Wb[i] = *(unsigned short*)&h;
  } else {
    Wb[i] = ((const unsigned short*)W)[i];
  }
  if (i < D_DIM) {
    biasf[i] = wfp ? ((const float*)b)[i] : (float)((const __bf16*)b)[i];
  }
}

// ---------------- Aggregation on X: Y[i] = di^2 X[i] + sum_e di*dc X[c] ----------------
// Also emits rowsum[i] = di^2 + sum_e di*dc (for the bias term).
// Y goes to d_out in the output dtype (== x dtype). One block per node.

__global__ __launch_bounds__(256) void aggregate_x_kernel(
    const void* __restrict__ X,
    const int* __restrict__ row_ptr,
    const int* __restrict__ cols,
    const float* __restrict__ dinv,
    const int* __restrict__ flags,
    float* __restrict__ rowsum,
    void* __restrict__ Y) {
  const int i  = blockIdx.x;
  const int c0 = threadIdx.x * 4;
  const float di = dinv[i];
  const int e0 = row_ptr[i], e1 = row_ptr[i + 1];
  float wsum = di * di;  // self-loop weight
  float a0, a1, a2, a3;

  if (flags[0]) {  // fp32 x, fp32 out
    const float* Xf = (const float*)X;
    f32x4 v = *(const f32x4*)(Xf + (size_t)i * D_DIM + c0);
    a0 = wsum * v[0]; a1 = wsum * v[1]; a2 = wsum * v[2]; a3 = wsum * v[3];
    for (int e = e0; e < e1; ++e) {
      int c = cols[e];
      float w = di * dinv[c];
      wsum += w;
      f32x4 u = *(const f32x4*)(Xf + (size_t)c * D_DIM + c0);
      a0 += w * u[0]; a1 += w * u[1]; a2 += w * u[2]; a3 += w * u[3];
    }
    f32x4 r; r[0] = a0; r[1] = a1; r[2] = a2; r[3] = a3;
    *(f32x4*)((float*)Y + (size_t)i * D_DIM + c0) = r;
  } else {         // bf16 x, bf16 out
    const __hip_bfloat16* Xb = (const __hip_bfloat16*)X;
    bf16x4 v = *(const bf16x4*)(Xb + (size_t)i * D_DIM + c0);
    a0 = wsum * (float)v[0]; a1 = wsum * (float)v[1];
    a2 = wsum * (float)v[2]; a3 = wsum * (float)v[3];
    for (int e = e0; e < e1; ++e) {
      int c = cols[e];
      float w = di * dinv[c];
      wsum += w;
      bf16x4 u = *(const bf16x4*)(Xb + (size_t)c * D_DIM + c0);
      a0 += w * (float)u[0]; a1 += w * (float)u[1];
      a2 += w * (float)u[2]; a3 += w * (float)u[3];
    }
    bf16x4 r;
    r[0] = (__bf16)a0; r[1] = (__bf16)a1; r[2] = (__bf16)a2; r[3] = (__bf16)a3;
    *(bf16x4*)((__hip_bfloat16*)Y + (size_t)i * D_DIM + c0) = r;
  }
  if (threadIdx.x == 0) rowsum[i] = wsum;
}

// ---------------- Strip GEMM: out[strip] = Y[strip] Wb^T + rowsum*b ----------------
// Block owns 32 rows of Y (in d_out). Stage to LDS as bf16 with 16B-chunk XOR
// swizzle, then 4 waves x 4 passes of 64 columns via mfma_f32_16x16x32_bf16.
// In-place on d_out: own rows only; reads via LDS before any write.

__global__ __launch_bounds__(256) void strip_gemm_kernel(
    const void* __restrict__ Yv,              // == out (read side)
    const unsigned short* __restrict__ Wb,    // [1024][1024] bf16, [o][k]
    const float* __restrict__ biasf,          // [1024]
    const float* __restrict__ rowsum,         // [M]
    const int* __restrict__ flags,
    void* __restrict__ outv) {                // == Y (write side)
  __shared__ unsigned short Ys[32 * 1024];    // 64 KB, chunk-swizzled

  const int t    = threadIdx.x;
  const int lane = t & 63;
  const int wave = t >> 6;
  const int m0   = blockIdx.x * 32;
  const int ofp  = flags[0];

  // ---- stage own 32 rows: 32*128 chunks of 8 values, 16 per thread ----
  if (ofp) {
    const float* Yf = (const float*)Yv;
    for (int idx = t; idx < 32 * 128; idx += 256) {
      int r = idx >> 7, c = idx & 127;
      const float* p = Yf + (size_t)(m0 + r) * D_DIM + c * 8;
      f32x4 lo = *(const f32x4*)p;
      f32x4 hi = *(const f32x4*)(p + 4);
      bf16x8 v;
      v[0] = (__bf16)lo[0]; v[1] = (__bf16)lo[1];
      v[2] = (__bf16)lo[2]; v[3] = (__bf16)lo[3];
      v[4] = (__bf16)hi[0]; v[5] = (__bf16)hi[1];
      v[6] = (__bf16)hi[2]; v[7] = (__bf16)hi[3];
      int sc = c ^ (r & 15);
      *(bf16x8*)&Ys[r * 1024 + sc * 8] = v;
    }
  } else {
    const __hip_bfloat16* Yb = (const __hip_bfloat16*)Yv;
    for (int idx = t; idx < 32 * 128; idx += 256) {
      int r = idx >> 7, c = idx & 127;
      bf16x8 v = *(const bf16x8*)(Yb + (size_t)(m0 + r) * D_DIM + c * 8);
      int sc = c ^ (r & 15);
      *(bf16x8*)&Ys[r * 1024 + sc * 8] = v;
    }
  }
  __syncthreads();

  const int quad = lane >> 4;   // k-subchunk 0..3
  const int mrow = lane & 15;   // row/col-in-tile

  for (int nb = 0; nb < 4; ++nb) {
    f32x4 acc[2][4] = {};
    for (int k0 = 0; k0 < D_DIM; k0 += 32) {
      const int cbase = k0 >> 3;
      bf16x8 a[2], b[4];
#pragma unroll
      for (int i = 0; i < 2; ++i) {
        int m = i * 16 + mrow;
        int sc = (cbase + quad) ^ mrow;     // m & 15 == mrow
        a[i] = *(const bf16x8*)&Ys[m * 1024 + sc * 8];
      }
#pragma unroll
      for (int j = 0; j < 4; ++j) {
        int n = wave * 256 + nb * 64 + j * 16 + mrow;
        b[j] = *(const bf16x8*)(Wb + (size_t)n * D_DIM + k0 + quad * 8);
      }
#pragma unroll
      for (int i = 0; i < 2; ++i)
#pragma unroll
        for (int j = 0; j < 4; ++j)
          acc[i][j] = __builtin_amdgcn_mfma_f32_16x16x32_bf16(a[i], b[j], acc[i][j], 0, 0, 0);
    }
    // epilogue: C/D layout col = lane&15 (=n), row = quad*4+reg (=m)
#pragma unroll
    for (int j = 0; j < 4; ++j) {
      int n = wave * 256 + nb * 64 + j * 16 + mrow;
      float bn = biasf[n];
#pragma unroll
      for (int i = 0; i < 2; ++i) {
        int mb = m0 + i * 16 + quad * 4;
#pragma unroll
        for (int rg = 0; rg < 4; ++rg) {
          int m = mb + rg;
          float val = acc[i][j][rg] + rowsum[m] * bn;
          if (ofp) ((float*)outv)[(size_t)m * D_DIM + n] = val;
          else ((__hip_bfloat16*)outv)[(size_t)m * D_DIM + n] = __float2bfloat16(val);
        }
      }
    }
  }
}

// ---------------- launch ----------------

extern "C" void kernel_launch(void* const* d_in, const int* in_sizes, int n_in,
                              void* d_out, int out_size, void* d_ws, size_t ws_size,
                              hipStream_t stream) {
  const void* x    = d_in[0];
  const void* ei   = d_in[1];
  const void* Wm   = d_in[2];
  const void* bias = d_in[3];

  const int E = in_sizes[1] / 2;
  const int M = in_sizes[0] / D_DIM;

  // workspace layout (~4 MB; re-poisoned every launch -> rebuild everything)
  char* ws = (char*)d_ws;
  int*   flags   = (int*)(ws);                          // 3 ints
  int*   cnt     = (int*)(ws + (size_t)(4 * 1024));     // M ints (80 KB)
  int*   row_ptr = (int*)(ws + (size_t)(128 * 1024));   // M+1 ints
  int*   cursor  = (int*)(ws + (size_t)(256 * 1024));
  float* dinv    = (float*)(ws + (size_t)(384 * 1024));
  float* rowsum  = (float*)(ws + (size_t)(512 * 1024));
  float* biasf   = (float*)(ws + (size_t)(640 * 1024)); // 4 KB
  int*   cols    = (int*)(ws + (size_t)(768 * 1024));   // E ints (1.25 MB)
  unsigned short* Wb = (unsigned short*)(ws + (size_t)(2 * 1024 * 1024)); // 2 MB

  detect_kernel<<<1, 256, 0, stream>>>((const unsigned int*)x,
                                       (const unsigned int*)Wm,
                                       (const unsigned int*)ei, flags);
  zero_cnt_kernel<<<(M + 255) / 256, 256, 0, stream>>>(cnt, M);
  count_deg_kernel<<<(E + 255) / 256, 256, 0, stream>>>(ei, E, flags, cnt);
  scan_kernel<<<1, 1024, 0, stream>>>(cnt, M, row_ptr, cursor, dinv);
  scatter_kernel<<<(E + 255) / 256, 256, 0, stream>>>(ei, E, flags, cursor, cols);
  conv_w_kernel<<<(D_DIM * D_DIM) / 256, 256, 0, stream>>>(Wm, bias, flags, Wb, biasf);

  aggregate_x_kernel<<<M, 256, 0, stream>>>(x, row_ptr, cols, dinv, flags,
                                            rowsum, d_out);
  strip_gemm_kernel<<<M / 32, 256, 0, stream>>>(d_out, Wb, biasf, rowsum,
                                                flags, d_out);
}

// Round 5
// 436.831 us; speedup vs baseline: 1.7522x; 1.7522x over previous
//
#include <hip/hip_runtime.h>
#include <hip/hip_bf16.h>
#include <stdint.h>
#include <stddef.h>

// GCNConv: out = S (X W^T + 1 b^T), S = D^-1/2 (A+I) D^-1/2
// Fast path (ws >= 48MB): H = X W^T + b  (bf16, MFMA 128x128 tiles, in ws),
//   then out[i] = sum_e w_e H[col] + dinv[i]^2 H[i]  (wave-per-node gather).
// Fallback (small ws): R4's aggregate-first + strip GEMM (proven).
// Dtypes detected on device: flags[0] x fp32?, flags[1] W fp32?, flags[2] int64 edges?

#define D_DIM 1024

typedef __bf16 bf16x8 __attribute__((ext_vector_type(8)));
typedef __bf16 bf16x4 __attribute__((ext_vector_type(4)));
typedef float  f32x4  __attribute__((ext_vector_type(4)));

#define GLOBAL_AS __attribute__((address_space(1)))
#define LDS_AS    __attribute__((address_space(3)))

static __device__ __forceinline__ void async_load16(const void* g, void* l) {
  __builtin_amdgcn_global_load_lds((GLOBAL_AS void*)(void*)g,
                                   (LDS_AS void*)l, 16, 0, 0);
}

// ---------------- dtype detection ----------------

__global__ void detect_kernel(const unsigned int* __restrict__ xw,
                              const unsigned int* __restrict__ ww,
                              const unsigned int* __restrict__ ew,
                              int* __restrict__ flags) {
  __shared__ int s[3];
  int t = threadIdx.x;
  if (t < 3) s[t] = 0;
  __syncthreads();
  int nx = 0, nw = 0, ze = 0;
  for (int i = t; i < 8192; i += 256) {
    if ((xw[i] & 0x7f80u) == 0x7f80u) nx++;
    if ((ww[i] & 0x7f80u) == 0x7f80u) nw++;
    if (ew[2 * i + 1] == 0u) ze++;
  }
  atomicAdd(&s[0], nx);
  atomicAdd(&s[1], nw);
  atomicAdd(&s[2], ze);
  __syncthreads();
  if (t == 0) {
    flags[0] = (s[0] >= 3) ? 1 : 0;
    flags[1] = (s[1] >= 3) ? 1 : 0;
    flags[2] = (s[2] >= 8000) ? 1 : 0;
  }
}

// ---------------- CSR construction ----------------

__global__ void zero_cnt_kernel(int* cnt, int n) {
  int i = blockIdx.x * blockDim.x + threadIdx.x;
  if (i < n) cnt[i] = 0;
}

__global__ void count_deg_kernel(const void* __restrict__ ei, int E,
                                 const int* __restrict__ flags,
                                 int* __restrict__ cnt) {
  int e = blockIdx.x * blockDim.x + threadIdx.x;
  if (e < E) {
    int r = flags[2] ? (int)((const long long*)ei)[e] : ((const int*)ei)[e];
    atomicAdd(&cnt[r], 1);
  }
}

__global__ void scan_kernel(const int* __restrict__ cnt, int n,
                            int* __restrict__ row_ptr, int* __restrict__ cursor,
                            float* __restrict__ dinv) {
  __shared__ int sdata[1024];
  __shared__ int carry_s;
  int t = threadIdx.x;
  if (t == 0) carry_s = 0;
  __syncthreads();
  for (int base = 0; base < n; base += 1024) {
    int idx = base + t;
    int v = (idx < n) ? cnt[idx] : 0;
    sdata[t] = v;
    __syncthreads();
    for (int off = 1; off < 1024; off <<= 1) {
      int add = (t >= off) ? sdata[t - off] : 0;
      __syncthreads();
      sdata[t] += add;
      __syncthreads();
    }
    int incl = sdata[t];
    int carry = carry_s;
    if (idx < n) {
      int excl = carry + incl - v;
      row_ptr[idx] = excl;
      cursor[idx]  = excl;
      dinv[idx] = rsqrtf((float)(v + 1));
    }
    __syncthreads();
    if (t == 1023) carry_s = carry + incl;
    __syncthreads();
  }
  if (t == 0) row_ptr[n] = carry_s;
}

// emit_w: also store per-edge weight dinv[r]*dinv[c] (fast path).
__global__ void scatter_kernel(const void* __restrict__ ei, int E,
                               const int* __restrict__ flags,
                               const float* __restrict__ dinv,
                               int* __restrict__ cursor,
                               int* __restrict__ cols_out,
                               float* __restrict__ wgt, int emit_w) {
  int e = blockIdx.x * blockDim.x + threadIdx.x;
  if (e < E) {
    int r, c;
    if (flags[2]) {
      const long long* p = (const long long*)ei;
      r = (int)p[e]; c = (int)p[e + E];
    } else {
      const int* p = (const int*)ei;
      r = p[e]; c = p[e + E];
    }
    int pos = atomicAdd(&cursor[r], 1);
    cols_out[pos] = c;
    if (emit_w) wgt[pos] = dinv[r] * dinv[c];
  }
}

// ---------------- canonicalize W (bf16) and bias (fp32) ----------------

__global__ void conv_w_kernel(const void* __restrict__ W,
                              const void* __restrict__ b,
                              const int* __restrict__ flags,
                              unsigned short* __restrict__ Wb,
                              float* __restrict__ biasf) {
  int i = blockIdx.x * blockDim.x + threadIdx.x;  // < 1M
  int wfp = flags[1];
  if (wfp) {
    __bf16 h = (__bf16)((const float*)W)[i];
    Wb[i] = *(unsigned short*)&h;
  } else {
    Wb[i] = ((const unsigned short*)W)[i];
  }
  if (i < D_DIM) {
    biasf[i] = wfp ? ((const float*)b)[i] : (float)((const __bf16*)b)[i];
  }
}

// ================= FAST PATH =================

// ---- GEMM: H[M][1024] (bf16) = X * Wb^T + bias ----
// 128x128 tile, BK=32, 4 waves 2x2, each wave 64x64 (4x4 x mfma 16x16x32).
// B staged async from Wb (ws, L2-hot); A staged manually with fp32->bf16 cvt.

__global__ __launch_bounds__(256) void gemm_xw_kernel(
    const void* __restrict__ Xv,
    const unsigned short* __restrict__ Wb,   // [1024][1024] bf16 [o][k]
    const float* __restrict__ biasf,
    const int* __restrict__ flags,
    __hip_bfloat16* __restrict__ H,          // [M][1024] bf16
    int M) {
  __shared__ unsigned short As[128 * 32];
  __shared__ unsigned short Bs[128 * 32];

  const int t    = threadIdx.x;
  const int lane = t & 63;
  const int wave = t >> 6;
  const int wm   = wave >> 1;
  const int wn   = wave & 1;
  const int m0   = blockIdx.x * 128;
  const int n0   = blockIdx.y * 128;
  const int xfp  = flags[0];

  f32x4 acc[4][4] = {};

  const int ra = t >> 1;          // A-staging row 0..127
  const int kh = (t & 1) * 16;    // A-staging k-half (16 elems)
  const int rb = t >> 2;          // B-staging row 0..63
  const int kc = (t & 3) * 8;     // B-staging k-chunk (8 elems = 16B)
  const int quad = lane >> 4;
  const int mrow = lane & 15;

  for (int k0 = 0; k0 < D_DIM; k0 += 32) {
    // B: async, Wb rows n0..n0+127 always in-bounds (N=1024)
    async_load16(Wb + (size_t)(n0 + rb) * D_DIM + k0 + kc, &Bs[rb * 32 + kc]);
    async_load16(Wb + (size_t)(n0 + rb + 64) * D_DIM + k0 + kc,
                 &Bs[(rb + 64) * 32 + kc]);
    // A: manual load + convert (zeros for OOB tail rows)
    bf16x8 lo{}, hi{};
    int gm = m0 + ra;
    if (gm < M) {
      if (xfp) {
        const float* p = (const float*)Xv + (size_t)gm * D_DIM + k0 + kh;
        f32x4 v0 = *(const f32x4*)(p);
        f32x4 v1 = *(const f32x4*)(p + 4);
        f32x4 v2 = *(const f32x4*)(p + 8);
        f32x4 v3 = *(const f32x4*)(p + 12);
        lo[0] = (__bf16)v0[0]; lo[1] = (__bf16)v0[1];
        lo[2] = (__bf16)v0[2]; lo[3] = (__bf16)v0[3];
        lo[4] = (__bf16)v1[0]; lo[5] = (__bf16)v1[1];
        lo[6] = (__bf16)v1[2]; lo[7] = (__bf16)v1[3];
        hi[0] = (__bf16)v2[0]; hi[1] = (__bf16)v2[1];
        hi[2] = (__bf16)v2[2]; hi[3] = (__bf16)v2[3];
        hi[4] = (__bf16)v3[0]; hi[5] = (__bf16)v3[1];
        hi[6] = (__bf16)v3[2]; hi[7] = (__bf16)v3[3];
      } else {
        const unsigned short* p =
            (const unsigned short*)Xv + (size_t)gm * D_DIM + k0 + kh;
        lo = *(const bf16x8*)p;
        hi = *(const bf16x8*)(p + 8);
      }
    }
    *(bf16x8*)&As[ra * 32 + kh]     = lo;
    *(bf16x8*)&As[ra * 32 + kh + 8] = hi;
    __syncthreads();

    bf16x8 a[4], b[4];
#pragma unroll
    for (int i = 0; i < 4; ++i)
      a[i] = *(const bf16x8*)&As[(wm * 64 + i * 16 + mrow) * 32 + quad * 8];
#pragma unroll
    for (int j = 0; j < 4; ++j)
      b[j] = *(const bf16x8*)&Bs[(wn * 64 + j * 16 + mrow) * 32 + quad * 8];
#pragma unroll
    for (int i = 0; i < 4; ++i)
#pragma unroll
      for (int j = 0; j < 4; ++j)
        acc[i][j] = __builtin_amdgcn_mfma_f32_16x16x32_bf16(a[i], b[j], acc[i][j], 0, 0, 0);
    __syncthreads();
  }

  // epilogue: C/D layout col = lane&15 (=n), row = quad*4+reg (=m)
#pragma unroll
  for (int j = 0; j < 4; ++j) {
    int n = n0 + wn * 64 + j * 16 + mrow;
    float bn = biasf[n];
#pragma unroll
    for (int i = 0; i < 4; ++i) {
      int mb = m0 + wm * 64 + i * 16 + quad * 4;
#pragma unroll
      for (int rg = 0; rg < 4; ++rg) {
        int m = mb + rg;
        if (m < M) H[(size_t)m * D_DIM + n] = __float2bfloat16(acc[i][j][rg] + bn);
      }
    }
  }
}

// ---- Aggregation over H: out[i] = dinv[i]^2 H[i] + sum_e wgt[e] H[col] ----
// Wave-per-node: 64 lanes x 16 cols. Coalesced 16B gathers, 64B fp32 stores.

__global__ __launch_bounds__(256) void aggregate_h_kernel(
    const __hip_bfloat16* __restrict__ H,
    const int* __restrict__ row_ptr,
    const int* __restrict__ cols,
    const float* __restrict__ wgt,
    const float* __restrict__ dinv,
    const int* __restrict__ flags,
    void* __restrict__ outv, int M) {
  const int lane = threadIdx.x & 63;
  const int i = blockIdx.x * 4 + (threadIdx.x >> 6);
  if (i >= M) return;
  const int c0 = lane * 16;

  float a[16];
  {
    float di = dinv[i];
    float w = di * di;
    const __hip_bfloat16* p = H + (size_t)i * D_DIM + c0;
    bf16x8 v0 = *(const bf16x8*)p;
    bf16x8 v1 = *(const bf16x8*)(p + 8);
#pragma unroll
    for (int k = 0; k < 8; ++k) {
      a[k]     = w * (float)v0[k];
      a[8 + k] = w * (float)v1[k];
    }
  }
  const int e0 = row_ptr[i], e1 = row_ptr[i + 1];
  for (int e = e0; e < e1; ++e) {
    int c = cols[e];
    float w = wgt[e];
    const __hip_bfloat16* p = H + (size_t)c * D_DIM + c0;
    bf16x8 u0 = *(const bf16x8*)p;
    bf16x8 u1 = *(const bf16x8*)(p + 8);
#pragma unroll
    for (int k = 0; k < 8; ++k) {
      a[k]     += w * (float)u0[k];
      a[8 + k] += w * (float)u1[k];
    }
  }
  if (flags[0]) {
    float* o = (float*)outv + (size_t)i * D_DIM + c0;
#pragma unroll
    for (int q = 0; q < 4; ++q) {
      f32x4 r; r[0] = a[4*q]; r[1] = a[4*q+1]; r[2] = a[4*q+2]; r[3] = a[4*q+3];
      *(f32x4*)(o + 4 * q) = r;
    }
  } else {
    __hip_bfloat16* o = (__hip_bfloat16*)outv + (size_t)i * D_DIM + c0;
    bf16x8 r0, r1;
#pragma unroll
    for (int k = 0; k < 8; ++k) { r0[k] = (__bf16)a[k]; r1[k] = (__bf16)a[8+k]; }
    *(bf16x8*)o = r0;
    *(bf16x8*)(o + 8) = r1;
  }
}

// ================= FALLBACK PATH (R4, proven) =================

__global__ __launch_bounds__(256) void aggregate_x_kernel(
    const void* __restrict__ X,
    const int* __restrict__ row_ptr,
    const int* __restrict__ cols,
    const float* __restrict__ dinv,
    const int* __restrict__ flags,
    float* __restrict__ rowsum,
    void* __restrict__ Y) {
  const int i  = blockIdx.x;
  const int c0 = threadIdx.x * 4;
  const float di = dinv[i];
  const int e0 = row_ptr[i], e1 = row_ptr[i + 1];
  float wsum = di * di;
  float a0, a1, a2, a3;

  if (flags[0]) {
    const float* Xf = (const float*)X;
    f32x4 v = *(const f32x4*)(Xf + (size_t)i * D_DIM + c0);
    a0 = wsum * v[0]; a1 = wsum * v[1]; a2 = wsum * v[2]; a3 = wsum * v[3];
    for (int e = e0; e < e1; ++e) {
      int c = cols[e];
      float w = di * dinv[c];
      wsum += w;
      f32x4 u = *(const f32x4*)(Xf + (size_t)c * D_DIM + c0);
      a0 += w * u[0]; a1 += w * u[1]; a2 += w * u[2]; a3 += w * u[3];
    }
    f32x4 r; r[0] = a0; r[1] = a1; r[2] = a2; r[3] = a3;
    *(f32x4*)((float*)Y + (size_t)i * D_DIM + c0) = r;
  } else {
    const __hip_bfloat16* Xb = (const __hip_bfloat16*)X;
    bf16x4 v = *(const bf16x4*)(Xb + (size_t)i * D_DIM + c0);
    a0 = wsum * (float)v[0]; a1 = wsum * (float)v[1];
    a2 = wsum * (float)v[2]; a3 = wsum * (float)v[3];
    for (int e = e0; e < e1; ++e) {
      int c = cols[e];
      float w = di * dinv[c];
      wsum += w;
      bf16x4 u = *(const bf16x4*)(Xb + (size_t)c * D_DIM + c0);
      a0 += w * (float)u[0]; a1 += w * (float)u[1];
      a2 += w * (float)u[2]; a3 += w * (float)u[3];
    }
    bf16x4 r;
    r[0] = (__bf16)a0; r[1] = (__bf16)a1; r[2] = (__bf16)a2; r[3] = (__bf16)a3;
    *(bf16x4*)((__hip_bfloat16*)Y + (size_t)i * D_DIM + c0) = r;
  }
  if (threadIdx.x == 0) rowsum[i] = wsum;
}

__global__ __launch_bounds__(256) void strip_gemm_kernel(
    const void* __restrict__ Yv,
    const unsigned short* __restrict__ Wb,
    const float* __restrict__ biasf,
    const float* __restrict__ rowsum,
    const int* __restrict__ flags,
    void* __restrict__ outv) {
  __shared__ unsigned short Ys[32 * 1024];

  const int t    = threadIdx.x;
  const int lane = t & 63;
  const int wave = t >> 6;
  const int m0   = blockIdx.x * 32;
  const int ofp  = flags[0];

  if (ofp) {
    const float* Yf = (const float*)Yv;
    for (int idx = t; idx < 32 * 128; idx += 256) {
      int r = idx >> 7, c = idx & 127;
      const float* p = Yf + (size_t)(m0 + r) * D_DIM + c * 8;
      f32x4 lo = *(const f32x4*)p;
      f32x4 hi = *(const f32x4*)(p + 4);
      bf16x8 v;
      v[0] = (__bf16)lo[0]; v[1] = (__bf16)lo[1];
      v[2] = (__bf16)lo[2]; v[3] = (__bf16)lo[3];
      v[4] = (__bf16)hi[0]; v[5] = (__bf16)hi[1];
      v[6] = (__bf16)hi[2]; v[7] = (__bf16)hi[3];
      int sc = c ^ (r & 15);
      *(bf16x8*)&Ys[r * 1024 + sc * 8] = v;
    }
  } else {
    const __hip_bfloat16* Yb = (const __hip_bfloat16*)Yv;
    for (int idx = t; idx < 32 * 128; idx += 256) {
      int r = idx >> 7, c = idx & 127;
      bf16x8 v = *(const bf16x8*)(Yb + (size_t)(m0 + r) * D_DIM + c * 8);
      int sc = c ^ (r & 15);
      *(bf16x8*)&Ys[r * 1024 + sc * 8] = v;
    }
  }
  __syncthreads();

  const int quad = lane >> 4;
  const int mrow = lane & 15;

  for (int nb = 0; nb < 4; ++nb) {
    f32x4 acc[2][4] = {};
    for (int k0 = 0; k0 < D_DIM; k0 += 32) {
      const int cbase = k0 >> 3;
      bf16x8 a[2], b[4];
#pragma unroll
      for (int i = 0; i < 2; ++i) {
        int m = i * 16 + mrow;
        int sc = (cbase + quad) ^ mrow;
        a[i] = *(const bf16x8*)&Ys[m * 1024 + sc * 8];
      }
#pragma unroll
      for (int j = 0; j < 4; ++j) {
        int n = wave * 256 + nb * 64 + j * 16 + mrow;
        b[j] = *(const bf16x8*)(Wb + (size_t)n * D_DIM + k0 + quad * 8);
      }
#pragma unroll
      for (int i = 0; i < 2; ++i)
#pragma unroll
        for (int j = 0; j < 4; ++j)
          acc[i][j] = __builtin_amdgcn_mfma_f32_16x16x32_bf16(a[i], b[j], acc[i][j], 0, 0, 0);
    }
#pragma unroll
    for (int j = 0; j < 4; ++j) {
      int n = wave * 256 + nb * 64 + j * 16 + mrow;
      float bn = biasf[n];
#pragma unroll
      for (int i = 0; i < 2; ++i) {
        int mb = m0 + i * 16 + quad * 4;
#pragma unroll
        for (int rg = 0; rg < 4; ++rg) {
          int m = mb + rg;
          float val = acc[i][j][rg] + rowsum[m] * bn;
          if (ofp) ((float*)outv)[(size_t)m * D_DIM + n] = val;
          else ((__hip_bfloat16*)outv)[(size_t)m * D_DIM + n] = __float2bfloat16(val);
        }
      }
    }
  }
}

// ---------------- launch ----------------

extern "C" void kernel_launch(void* const* d_in, const int* in_sizes, int n_in,
                              void* d_out, int out_size, void* d_ws, size_t ws_size,
                              hipStream_t stream) {
  const void* x    = d_in[0];
  const void* ei   = d_in[1];
  const void* Wm   = d_in[2];
  const void* bias = d_in[3];

  const int E = in_sizes[1] / 2;
  const int M = in_sizes[0] / D_DIM;

  char* ws = (char*)d_ws;
  const size_t KB = 1024, MB = 1024 * 1024;

  const size_t need_fast = 6 * MB + (size_t)M * D_DIM * 2 + MB;  // H + slack

  if (ws_size >= need_fast) {
    // fast layout
    int*   flags   = (int*)(ws);
    int*   cnt     = (int*)(ws + 4 * KB);
    int*   row_ptr = (int*)(ws + 128 * KB);
    int*   cursor  = (int*)(ws + 256 * KB);
    float* dinv    = (float*)(ws + 384 * KB);
    float* biasf   = (float*)(ws + 512 * KB);
    int*   cols    = (int*)(ws + 768 * KB);          // 1.25 MB
    float* wgt     = (float*)(ws + 2 * MB);          // 1.25 MB
    unsigned short* Wb = (unsigned short*)(ws + 4 * MB);  // 2 MB
    __hip_bfloat16* H  = (__hip_bfloat16*)(ws + 6 * MB);  // 40.96 MB

    detect_kernel<<<1, 256, 0, stream>>>((const unsigned int*)x,
                                         (const unsigned int*)Wm,
                                         (const unsigned int*)ei, (int*)flags);
    zero_cnt_kernel<<<(M + 255) / 256, 256, 0, stream>>>(cnt, M);
    count_deg_kernel<<<(E + 255) / 256, 256, 0, stream>>>(ei, E, flags, cnt);
    scan_kernel<<<1, 1024, 0, stream>>>(cnt, M, row_ptr, cursor, dinv);
    scatter_kernel<<<(E + 255) / 256, 256, 0, stream>>>(ei, E, flags, dinv,
                                                        cursor, cols, wgt, 1);
    conv_w_kernel<<<(D_DIM * D_DIM) / 256, 256, 0, stream>>>(Wm, bias, flags,
                                                             Wb, biasf);
    dim3 ggrid((M + 127) / 128, D_DIM / 128);
    gemm_xw_kernel<<<ggrid, 256, 0, stream>>>(x, Wb, biasf, flags, H, M);
    aggregate_h_kernel<<<(M + 3) / 4, 256, 0, stream>>>(H, row_ptr, cols, wgt,
                                                        dinv, flags, d_out, M);
  } else {
    // fallback layout (R4)
    int*   flags   = (int*)(ws);
    int*   cnt     = (int*)(ws + 4 * KB);
    int*   row_ptr = (int*)(ws + 128 * KB);
    int*   cursor  = (int*)(ws + 256 * KB);
    float* dinv    = (float*)(ws + 384 * KB);
    float* rowsum  = (float*)(ws + 512 * KB);
    float* biasf   = (float*)(ws + 640 * KB);
    int*   cols    = (int*)(ws + 768 * KB);
    unsigned short* Wb = (unsigned short*)(ws + 2 * MB);

    detect_kernel<<<1, 256, 0, stream>>>((const unsigned int*)x,
                                         (const unsigned int*)Wm,
                                         (const unsigned int*)ei, (int*)flags);
    zero_cnt_kernel<<<(M + 255) / 256, 256, 0, stream>>>(cnt, M);
    count_deg_kernel<<<(E + 255) / 256, 256, 0, stream>>>(ei, E, flags, cnt);
    scan_kernel<<<1, 1024, 0, stream>>>(cnt, M, row_ptr, cursor, dinv);
    scatter_kernel<<<(E + 255) / 256, 256, 0, stream>>>(ei, E, flags, dinv,
                                                        cursor, cols, (float*)0, 0);
    conv_w_kernel<<<(D_DIM * D_DIM) / 256, 256, 0, stream>>>(Wm, bias, flags,
                                                             Wb, biasf);
    aggregate_x_kernel<<<M, 256, 0, stream>>>(x, row_ptr, cols, dinv, flags,
                                              rowsum, d_out);
    strip_gemm_kernel<<<M / 32, 256, 0, stream>>>(d_out, Wb, biasf, rowsum,
                                                  flags, d_out);
  }
}